// Round 12
// baseline (367.723 us; speedup 1.0000x reference)
//
#include <hip/hip_runtime.h>
#include <hip/hip_bf16.h>
#include <math.h>

#define NN  20000
#define FF  128
#define EMB 128
#define HH  3
#define GG  128
#define HD  384   // H*EMB
#define ELL 64    // max degree capacity (deg = 1+Poisson(16); P(>64) ~ 1e-14)
#define NUNITS 2500   // 2*NN/16
#define NLB    1250   // grid: each block does units bid and bid+NLB (same parity)

typedef __attribute__((ext_vector_type(8))) short short8;
typedef __attribute__((ext_vector_type(4))) float f32x4;

__device__ inline float bf2f(unsigned int u){
  union{unsigned int i; float f;} v; v.i = u<<16; return v.f;
}
__device__ inline unsigned short f2bf(float f){
  union{unsigned int i; float f;} v; v.f = f;
  unsigned r = v.i + 0x7FFFu + ((v.i>>16)&1u);
  return (unsigned short)(r>>16);
}

// ---------------- prep: MT, V, cbuf + ELL count_fill (one launch) ----------------
// blocks [0,48): MT; [48,816): V; [816,944): cbuf; [944, 944+2*nbE): count_fill
__global__ __launch_bounds__(256) void prep(
    const float* __restrict__ W1A, const float* __restrict__ al1A, const float* __restrict__ ar1A,
    const float* __restrict__ WnA, const float* __restrict__ alnA, const float* __restrict__ arnA,
    const float* __restrict__ W1B, const float* __restrict__ al1B, const float* __restrict__ ar1B,
    const float* __restrict__ WnB, const float* __restrict__ alnB, const float* __restrict__ arnB,
    const float* __restrict__ WlA, const float* __restrict__ blA,
    const float* __restrict__ WlB, const float* __restrict__ blB,
    const float* __restrict__ b1A, const float* __restrict__ bnA,
    const float* __restrict__ b1B, const float* __restrict__ bnB,
    unsigned short* __restrict__ MT, float* __restrict__ V, float* __restrict__ cbuf,
    const int* __restrict__ srcA, const int* __restrict__ dstA,
    const int* __restrict__ srcB, const int* __restrict__ dstB,
    int* __restrict__ cntA, int* __restrict__ cntB,
    int* __restrict__ slotA, int* __restrict__ slotB, int ne, int nbE){
  __shared__ float As[32][65];   // [d][p]
  __shared__ float Bs[32][65];   // [d][q]
  int bid = blockIdx.x;
  int wv = threadIdx.x >> 6, lane = threadIdx.x & 63;

  if (bid < 48){
    // composed weights MT[mat][q][h*128+p] = sum_d W[p][h*128+d]*Wl[h*128+d][q]
    int mh = bid >> 2;
    int mat = mh / 3, h = mh - mat*3;
    int tile = bid & 3; int tp = (tile>>1)*64, tq = (tile&1)*64;
    const float* W  = (mat==0)?W1A:(mat==1)?WnA:(mat==2)?W1B:WnB;
    const float* Wl = (mat<2)? WlA : WlB;
    int tid = threadIdx.x;
    int tq4 = (tid&15)<<2, tp4 = (tid>>4)<<2;
    float acc[4][4] = {};
    for (int d0=0; d0<128; d0+=32){
      {
        int p = tid>>3, dd = (tid&7)<<2;
        float4 a0 = *(const float4*)&W[(size_t)(tp+p)*HD + h*128 + d0 + dd];
        float4 a1 = *(const float4*)&W[(size_t)(tp+p+32)*HD + h*128 + d0 + dd];
        As[dd+0][p]=a0.x; As[dd+1][p]=a0.y; As[dd+2][p]=a0.z; As[dd+3][p]=a0.w;
        As[dd+0][p+32]=a1.x; As[dd+1][p+32]=a1.y; As[dd+2][p+32]=a1.z; As[dd+3][p+32]=a1.w;
      }
      {
        int dd = tid>>4, q4 = (tid&15)<<2;
        float4 b0 = *(const float4*)&Wl[(size_t)(h*128+d0+dd)*128 + tq + q4];
        float4 b1 = *(const float4*)&Wl[(size_t)(h*128+d0+dd+16)*128 + tq + q4];
        Bs[dd][q4+0]=b0.x; Bs[dd][q4+1]=b0.y; Bs[dd][q4+2]=b0.z; Bs[dd][q4+3]=b0.w;
        Bs[dd+16][q4+0]=b1.x; Bs[dd+16][q4+1]=b1.y; Bs[dd+16][q4+2]=b1.z; Bs[dd+16][q4+3]=b1.w;
      }
      __syncthreads();
      #pragma unroll
      for (int k=0;k<32;k++){
        float a[4], bb[4];
        #pragma unroll
        for (int i=0;i<4;i++) a[i] = As[k][tp4+i];
        #pragma unroll
        for (int jq=0;jq<4;jq++) bb[jq] = Bs[k][tq4+jq];
        #pragma unroll
        for (int i=0;i<4;i++)
          #pragma unroll
          for (int jq=0;jq<4;jq++)
            acc[i][jq] += a[i]*bb[jq];
      }
      __syncthreads();
    }
    #pragma unroll
    for (int jq=0;jq<4;jq++)
      #pragma unroll
      for (int i=0;i<4;i++)
        MT[(size_t)mat*49152 + (size_t)(tq+tq4+jq)*HD + h*128 + tp+tp4+i] = f2bf(acc[i][jq]);
  } else if (bid < 816){
    int idx = (bid-48)*4 + wv;
    int mat = idx / 768; int rem = idx - mat*768;
    int j = rem >> 7, k = rem & 127;
    int h = (j >= 3) ? j-3 : j; bool isr = j >= 3;
    const float* W = (mat==0)?W1A:(mat==1)?WnA:(mat==2)?W1B:WnB;
    const float* a;
    if (mat==0)      a = isr?ar1A:al1A;
    else if (mat==1) a = isr?arnA:alnA;
    else if (mat==2) a = isr?ar1B:al1B;
    else             a = isr?arnB:alnB;
    float s = W[(size_t)k*HD + h*128 + lane]      * a[h*128 + lane]
            + W[(size_t)k*HD + h*128 + 64 + lane] * a[h*128 + 64 + lane];
    #pragma unroll
    for (int o=32;o;o>>=1) s += __shfl_xor(s,o);
    if (lane == 0) V[(size_t)mat*768 + j*128 + k] = s;
  } else if (bid < 944){
    int idx = (bid-816)*4 + wv;
    int mat = idx >> 7, q = idx & 127;
    const float* bvec = (mat==0)?b1A:(mat==1)?bnA:(mat==2)?b1B:bnB;
    const float* Wl = (mat<2)?WlA:WlB;
    const float* bl = (mat<2)?blA:blB;
    float s = 0.f;
    #pragma unroll
    for (int r=0;r<6;r++){
      int j = r*64 + lane;
      s += bvec[j]*Wl[(size_t)j*128 + q];
    }
    #pragma unroll
    for (int o=32;o;o>>=1) s += __shfl_xor(s,o);
    if (lane == 0) cbuf[mat*128 + q] = s + bl[q];
  } else {
    int bb = bid - 944; int isB = bb >= nbE;
    const int* src = isB ? srcB : srcA;
    const int* dst = isB ? dstB : dstA;
    int* cnt  = isB ? cntB : cntA;
    int* slot = isB ? slotB : slotA;
    int i = (isB ? bb-nbE : bb)*256 + threadIdx.x;
    if (i < ne){
      int d = dst[i];
      int p = atomicAdd(&cnt[d], 1);
      if (p < ELL) __builtin_nontemporal_store(src[i], &slot[d*ELL + p]);
    }
  }
}

// ---------------- conv feats -> bf16, fused layer-1 el/er ----------------
__global__ __launch_bounds__(256) void conv_elr1(
    const float* __restrict__ fA, const float* __restrict__ fB,
    unsigned short* __restrict__ XA, unsigned short* __restrict__ XB,
    const float* __restrict__ V,
    float* __restrict__ el, float* __restrict__ er){
  int gn = blockIdx.x*4 + (threadIdx.x>>6);      // 0..2*NN-1
  int lane = threadIdx.x & 63;
  int b = gn >= NN; int n = b ? gn - NN : gn;
  const float* feats = b ? fB : fA;
  unsigned short* X = b ? XB : XA;
  const float* Vb = V + (size_t)(b*2 + 0)*768;
  float2 xv = ((const float2*)feats)[(size_t)n*64 + lane];
  ((unsigned*)(X + (size_t)n*EMB))[lane] =
      (unsigned)f2bf(xv.x) | ((unsigned)f2bf(xv.y)<<16);
  float x0 = bf2f((unsigned)f2bf(xv.x)), x1 = bf2f((unsigned)f2bf(xv.y));
  int c0 = 2*lane;
  #pragma unroll
  for (int j=0;j<6;j++){
    float v = x0*Vb[j*128 + c0] + x1*Vb[j*128 + c0 + 1];
    #pragma unroll
    for (int o=32;o;o>>=1) v += __shfl_xor(v,o);
    if (lane == 0){
      if (j < 3) el[(size_t)gn*4 + j] = v;
      else       er[(size_t)gn*4 + (j-3)] = v;
    }
  }
}

// ---------------- fused GAT layer: pair-interleaved gather -> LDS U -> MFMA ----
// grid = NLB blocks; each block processes units bid and bid+NLB (same branch parity).
// unit: branch = unit&1 (XCD parity), node base = (unit>>1)*16
__global__ __launch_bounds__(256) void layer_fused(
    const unsigned short* __restrict__ X0, const unsigned short* __restrict__ X1,
    const float* __restrict__ el, const float* __restrict__ er,
    const int* __restrict__ cntA, const int* __restrict__ cntB,
    const int* __restrict__ slotA, const int* __restrict__ slotB,
    const unsigned short* __restrict__ MT_A, const unsigned short* __restrict__ MT_B,
    const float* __restrict__ cb_A, const float* __restrict__ cb_B,
    const float* __restrict__ V, int vsel,
    float* __restrict__ elN, float* __restrict__ erN,
    unsigned short* __restrict__ Xo0, unsigned short* __restrict__ Xo1){
  __shared__ unsigned short Ul[16][392];     // 16 x (384+8 pad) bf16 = 12.25 KB
  __shared__ float part[4][16][6];           // elr partials
  int wv = threadIdx.x >> 6, lane = threadIdx.x & 63;

  for (int unit = blockIdx.x; unit < NUNITS; unit += NLB){
    if (unit != (int)blockIdx.x) __syncthreads();   // protect Ul reuse across units
    int b = unit & 1;                        // XCD parity: one branch per XCD
    int base = (unit >> 1) * 16;
    const unsigned short* X = b ? X1 : X0;
    const int* cnt  = b ? cntB : cntA;
    const int* slot = b ? slotB : slotA;
    const float* elb = el + (size_t)b*NN*4;
    const float* erb = er + (size_t)b*NN*4;
    const unsigned* Xw = (const unsigned*)X;

    // ---- phase 1: two node-pairs; softmax interleaved, aggregation 8 chains ----
    #pragma unroll
    for (int pp = 0; pp < 2; pp++){
      int dg_[2]; int s_[2]; float e_[2][3];
      #pragma unroll
      for (int j=0;j<2;j++){
        int n = base + wv*4 + pp*2 + j;
        int dg = cnt[n]; if (dg > ELL) dg = ELL;
        dg_[j] = dg;
        float4 ev4 = *(const float4*)(erb + (size_t)n*4);
        int s = 0;
        float q0=-3e38f, q1=-3e38f, q2=-3e38f;
        if (lane < dg){
          s = slot[n*ELL + lane];
          float4 lv = *(const float4*)(elb + (size_t)s*4);
          float t0 = lv.x+ev4.x; q0 = t0>0.f ? t0 : 0.2f*t0;
          float t1 = lv.y+ev4.y; q1 = t1>0.f ? t1 : 0.2f*t1;
          float t2 = lv.z+ev4.z; q2 = t2>0.f ? t2 : 0.2f*t2;
        }
        s_[j] = s; e_[j][0]=q0; e_[j][1]=q1; e_[j][2]=q2;
      }
      float m_[2][3];
      #pragma unroll
      for (int j=0;j<2;j++)
        #pragma unroll
        for (int h=0;h<3;h++) m_[j][h] = e_[j][h];
      #pragma unroll
      for (int o=32;o;o>>=1)
        #pragma unroll
        for (int j=0;j<2;j++)
          #pragma unroll
          for (int h=0;h<3;h++) m_[j][h] = fmaxf(m_[j][h], __shfl_xor(m_[j][h],o));
      float p_[2][3], d_[2][3];
      #pragma unroll
      for (int j=0;j<2;j++)
        #pragma unroll
        for (int h=0;h<3;h++){ p_[j][h] = __expf(e_[j][h]-m_[j][h]); d_[j][h] = p_[j][h]; }
      #pragma unroll
      for (int o=32;o;o>>=1)
        #pragma unroll
        for (int j=0;j<2;j++)
          #pragma unroll
          for (int h=0;h<3;h++) d_[j][h] += __shfl_xor(d_[j][h],o);
      int ai_[2][3];
      #pragma unroll
      for (int j=0;j<2;j++)
        #pragma unroll
        for (int h=0;h<3;h++) ai_[j][h] = __float_as_int(p_[j][h]/d_[j][h]);

      // aggregation: 2 nodes x unroll-4 = 8 gathers in flight
      int degmax = dg_[0] > dg_[1] ? dg_[0] : dg_[1];
      int npad = (degmax + 3) & ~3;
      float acc_[2][6] = {};
      for (int e4 = 0; e4 < npad; e4 += 4){
        #pragma unroll
        for (int u = 0; u < 4; u++){
          int idx = e4 + u;
          #pragma unroll
          for (int j=0;j<2;j++){
            int sl = __builtin_amdgcn_readlane(s_[j], idx);
            float w0 = __int_as_float(__builtin_amdgcn_readlane(ai_[j][0], idx));
            float w1 = __int_as_float(__builtin_amdgcn_readlane(ai_[j][1], idx));
            float w2 = __int_as_float(__builtin_amdgcn_readlane(ai_[j][2], idx));
            unsigned xu = Xw[(size_t)sl*64 + lane];
            float lo = __int_as_float(xu << 16);
            float hi = __int_as_float(xu & 0xffff0000u);
            acc_[j][0] += w0*lo; acc_[j][1] += w0*hi;
            acc_[j][2] += w1*lo; acc_[j][3] += w1*hi;
            acc_[j][4] += w2*lo; acc_[j][5] += w2*hi;
          }
        }
      }
      #pragma unroll
      for (int j=0;j<2;j++){
        unsigned* urow = (unsigned*)&Ul[wv*4 + pp*2 + j][0];
        urow[lane]     = (unsigned)f2bf(acc_[j][0]) | ((unsigned)f2bf(acc_[j][1])<<16);
        urow[64+lane]  = (unsigned)f2bf(acc_[j][2]) | ((unsigned)f2bf(acc_[j][3])<<16);
        urow[128+lane] = (unsigned)f2bf(acc_[j][4]) | ((unsigned)f2bf(acc_[j][5])<<16);
      }
    }
    __syncthreads();

    // ---- phase 2: C[16 nodes][128] = U[16][384] @ M[384][128] via MFMA ----
    int l16 = lane & 15, lq = lane >> 4;
    const unsigned short* MTb = b ? MT_B : MT_A;
    int col0 = wv*32 + l16;
    int col1 = col0 + 16;
    const unsigned short* bp0 = MTb + (size_t)col0*HD + lq*8;
    const unsigned short* bp1 = MTb + (size_t)col1*HD + lq*8;
    f32x4 acc0 = {0.f,0.f,0.f,0.f}, acc1 = {0.f,0.f,0.f,0.f};
    #pragma unroll
    for (int k0 = 0; k0 < HD; k0 += 32){
      short8 af = *(const short8*)&Ul[l16][k0 + lq*8];
      short8 b0 = *(const short8*)&bp0[k0];
      short8 b1 = *(const short8*)&bp1[k0];
      acc0 = __builtin_amdgcn_mfma_f32_16x16x32_bf16(af, b0, acc0, 0, 0, 0);
      acc1 = __builtin_amdgcn_mfma_f32_16x16x32_bf16(af, b1, acc1, 0, 0, 0);
    }

    // ---- epilogue: bias, bf16 round, store X_next, elr_next ----
    const float* cbb = b ? cb_B : cb_A;
    unsigned short* Xout = b ? Xo1 : Xo0;
    float cv0 = cbb[col0], cv1 = cbb[col1];
    float vv0[6], vv1[6];
    if (vsel >= 0){
      const float* Vv = V + (size_t)(b*2 + vsel)*768;
      #pragma unroll
      for (int j=0;j<6;j++){ vv0[j] = Vv[j*128 + col0]; vv1[j] = Vv[j*128 + col1]; }
    }
    #pragma unroll
    for (int r = 0; r < 4; r++){
      int nloc = lq*4 + r;
      int n = base + nloc;
      float x0 = acc0[r] + cv0, x1 = acc1[r] + cv1;
      unsigned short xb0 = f2bf(x0), xb1 = f2bf(x1);
      Xout[(size_t)n*EMB + col0] = xb0;
      Xout[(size_t)n*EMB + col1] = xb1;
      if (vsel >= 0){
        float xr0 = bf2f(xb0), xr1 = bf2f(xb1);
        float p[6];
        #pragma unroll
        for (int j=0;j<6;j++) p[j] = xr0*vv0[j] + xr1*vv1[j];
        #pragma unroll
        for (int j=0;j<6;j++){
          #pragma unroll
          for (int o=1;o<16;o<<=1) p[j] += __shfl_xor(p[j], o);
        }
        if (l16 == 0){
          #pragma unroll
          for (int j=0;j<6;j++) part[wv][nloc][j] = p[j];
        }
      }
    }
    if (vsel >= 0){
      __syncthreads();
      int t = threadIdx.x;
      if (t < 96){
        int nloc = t / 6, j = t - (t/6)*6;
        float s2 = part[0][nloc][j] + part[1][nloc][j] + part[2][nloc][j] + part[3][nloc][j];
        size_t gn = (size_t)b*NN + base + nloc;
        if (j < 3) elN[gn*4 + j] = s2;
        else       erN[gn*4 + (j-3)] = s2;
      }
    }
  }
}

// ---------------- pooling: contiguous segments via binary search, no atomics ----
__device__ inline int lbound(const int* __restrict__ a, int n, int v){
  int lo = 0, hi = n;
  while (lo < hi){ int mid = (lo+hi)>>1; if (a[mid] < v) lo = mid+1; else hi = mid; }
  return lo;
}

__global__ __launch_bounds__(512) void pool_kernel(
    const unsigned short* __restrict__ X0, const unsigned short* __restrict__ X1,
    const int* __restrict__ gidA, const int* __restrict__ gidB,
    float* __restrict__ ps){
  int bg = blockIdx.x;                 // 0..2*GG-1
  int b = bg >= GG; int g = b ? bg-GG : bg;
  const unsigned short* X = b ? X1 : X0;
  const int* gid = b ? gidB : gidA;
  int lo = lbound(gid, NN, g), hi = lbound(gid, NN, g+1);
  int t = threadIdx.x;
  int rl = t >> 6, c2 = t & 63;        // 8 row-lanes x 64 u32-cols
  float ax = 0.f, ay = 0.f;
  for (int n = lo + rl; n < hi; n += 8){
    unsigned u = ((const unsigned*)(X + (size_t)n*EMB))[c2];
    ax += bf2f(u & 0xFFFFu); ay += bf2f(u >> 16);
  }
  __shared__ float sh[8][128];
  sh[rl][2*c2] = ax; sh[rl][2*c2+1] = ay;
  __syncthreads();
  if (t < 128){
    float s = 0.f;
    #pragma unroll
    for (int r=0;r<8;r++) s += sh[r][t];
    ps[(size_t)bg*EMB + t] = s / (float)(hi - lo);
  }
}

// ---------------- final ----------------
__global__ void final_kernel(const float* __restrict__ ps,
                             const float* __restrict__ Wo, const float* __restrict__ bo,
                             float* __restrict__ out){
  int g = blockIdx.x*4 + (threadIdx.x>>6);
  int lane = threadIdx.x & 63;
  if (g >= GG) return;
  float v = 0.f;
  #pragma unroll
  for (int r=0;r<4;r++){
    int k = r*64 + lane;
    float cv = (k < EMB) ? ps[(size_t)g*EMB + k]
                         : ps[(size_t)(GG + g)*EMB + (k-EMB)];
    v += cv * Wo[k];
  }
  #pragma unroll
  for (int o=32;o;o>>=1) v += __shfl_xor(v,o);
  if (lane == 0) out[g] = v + bo[0];
}

// ---------------- launcher ----------------
extern "C" void kernel_launch(void* const* d_in, const int* in_sizes, int n_in,
                              void* d_out, int out_size, void* d_ws, size_t ws_size,
                              hipStream_t stream){
  const float* featsA = (const float*)d_in[0];
  const float* featsB = (const float*)d_in[1];
  const int* srcA = (const int*)d_in[2];
  const int* dstA = (const int*)d_in[3];
  const int* gidA = (const int*)d_in[4];
  const int* srcB = (const int*)d_in[5];
  const int* dstB = (const int*)d_in[6];
  const int* gidB = (const int*)d_in[7];
  const int EE = in_sizes[2];
  const float* P[2][10];
  for (int b=0;b<2;b++)
    for (int j=0;j<10;j++)
      P[b][j] = (const float*)d_in[8 + b*10 + j];
  const float* Wo = (const float*)d_in[28];
  const float* bo = (const float*)d_in[29];
  float* out = (float*)d_out;

  char* ws = (char*)d_ws;
  size_t o = 0;
  auto alloc = [&](size_t bytes)->char*{
    char* p = ws + o; o += (bytes + 255) & ~(size_t)255; return p;
  };
  unsigned short* fbf[2] = {(unsigned short*)alloc((size_t)NN*FF*2),
                            (unsigned short*)alloc((size_t)NN*FF*2)};
  unsigned short* Xa[2] = {(unsigned short*)alloc((size_t)NN*EMB*2),
                           (unsigned short*)alloc((size_t)NN*EMB*2)};
  unsigned short* Xb[2] = {(unsigned short*)alloc((size_t)NN*EMB*2),
                           (unsigned short*)alloc((size_t)NN*EMB*2)};
  unsigned short* MT = (unsigned short*)alloc((size_t)4*49152*2);
  float* V    = (float*)alloc((size_t)4*768*4);
  float* cbuf = (float*)alloc((size_t)4*128*4);
  float* el0  = (float*)alloc((size_t)2*NN*4*4);
  float* er0  = (float*)alloc((size_t)2*NN*4*4);
  float* el1  = (float*)alloc((size_t)2*NN*4*4);
  float* er1  = (float*)alloc((size_t)2*NN*4*4);
  float* el2  = (float*)alloc((size_t)2*NN*4*4);
  float* er2  = (float*)alloc((size_t)2*NN*4*4);
  int*   cntA = (int*)alloc((size_t)2*NN*4);
  int*   cntB = cntA + NN;
  int*   slotA= (int*)alloc((size_t)NN*ELL*4);
  int*   slotB= (int*)alloc((size_t)NN*ELL*4);
  float* ps   = (float*)alloc((size_t)2*GG*EMB*4);

  const int nbE = (EE + 255)/256;
  const int nwB = 2*NN/4;

  hipMemsetAsync(cntA, 0, (size_t)2*NN*4, stream);
  prep<<<944 + 2*nbE, 256, 0, stream>>>(
      P[0][0],P[0][1],P[0][2], P[0][4],P[0][5],P[0][6],
      P[1][0],P[1][1],P[1][2], P[1][4],P[1][5],P[1][6],
      P[0][8],P[0][9], P[1][8],P[1][9],
      P[0][3],P[0][7], P[1][3],P[1][7],
      MT, V, cbuf,
      srcA,dstA, srcB,dstB, cntA,cntB, slotA,slotB, EE, nbE);
  conv_elr1<<<nwB,256,0,stream>>>(featsA, featsB, fbf[0], fbf[1], V, el0, er0);

  // layer 1: X=feats, M = composed(W1,Wl), elr_next via V lsel=1
  layer_fused<<<NLB,256,0,stream>>>(fbf[0], fbf[1], el0, er0, cntA,cntB, slotA,slotB,
                                    MT + 0*49152, MT + 2*49152,
                                    cbuf + 0*128, cbuf + 2*128,
                                    V, 1, el1, er1, Xa[0], Xa[1]);
  // layer 2: M = composed(Wn,Wl)
  layer_fused<<<NLB,256,0,stream>>>(Xa[0], Xa[1], el1, er1, cntA,cntB, slotA,slotB,
                                    MT + 1*49152, MT + 3*49152,
                                    cbuf + 1*128, cbuf + 3*128,
                                    V, 1, el2, er2, Xb[0], Xb[1]);
  // layer 3: no elr_next
  layer_fused<<<NLB,256,0,stream>>>(Xb[0], Xb[1], el2, er2, cntA,cntB, slotA,slotB,
                                    MT + 1*49152, MT + 3*49152,
                                    cbuf + 1*128, cbuf + 3*128,
                                    V, -1, nullptr, nullptr, Xa[0], Xa[1]);

  // pooling + final
  pool_kernel<<<2*GG,512,0,stream>>>(Xa[0],Xa[1], gidA,gidB, ps);
  final_kernel<<<(GG+3)/4,256,0,stream>>>(ps, Wo, bo, out);
}

// Round 13
// 351.814 us; speedup vs baseline: 1.0452x; 1.0452x over previous
//
#include <hip/hip_runtime.h>
#include <hip/hip_bf16.h>
#include <math.h>

#define NN  20000
#define FF  128
#define EMB 128
#define HH  3
#define GG  128
#define HD  384   // H*EMB
#define ELL 64    // max degree capacity (deg = 1+Poisson(16); P(>64) ~ 1e-14)
#define NLB 1250  // layer grid; each block does node-halves base and base+10000 (same branch)

typedef __attribute__((ext_vector_type(8))) short short8;
typedef __attribute__((ext_vector_type(4))) float f32x4;

__device__ inline float bf2f(unsigned int u){
  union{unsigned int i; float f;} v; v.i = u<<16; return v.f;
}
__device__ inline unsigned short f2bf(float f){
  union{unsigned int i; float f;} v; v.f = f;
  unsigned r = v.i + 0x7FFFu + ((v.i>>16)&1u);
  return (unsigned short)(r>>16);
}

// ---------------- prep: MT, V, cbuf + ELL count_fill (one launch) ----------------
// blocks [0,48): MT; [48,816): V; [816,944): cbuf; [944, 944+2*nbE): count_fill
__global__ __launch_bounds__(256) void prep(
    const float* __restrict__ W1A, const float* __restrict__ al1A, const float* __restrict__ ar1A,
    const float* __restrict__ WnA, const float* __restrict__ alnA, const float* __restrict__ arnA,
    const float* __restrict__ W1B, const float* __restrict__ al1B, const float* __restrict__ ar1B,
    const float* __restrict__ WnB, const float* __restrict__ alnB, const float* __restrict__ arnB,
    const float* __restrict__ WlA, const float* __restrict__ blA,
    const float* __restrict__ WlB, const float* __restrict__ blB,
    const float* __restrict__ b1A, const float* __restrict__ bnA,
    const float* __restrict__ b1B, const float* __restrict__ bnB,
    unsigned short* __restrict__ MT, float* __restrict__ V, float* __restrict__ cbuf,
    const int* __restrict__ srcA, const int* __restrict__ dstA,
    const int* __restrict__ srcB, const int* __restrict__ dstB,
    int* __restrict__ cntA, int* __restrict__ cntB,
    int* __restrict__ slotA, int* __restrict__ slotB, int ne, int nbE){
  __shared__ float As[32][65];   // [d][p]
  __shared__ float Bs[32][65];   // [d][q]
  int bid = blockIdx.x;
  int wv = threadIdx.x >> 6, lane = threadIdx.x & 63;

  if (bid < 48){
    // composed weights MT[mat][q][h*128+p] = sum_d W[p][h*128+d]*Wl[h*128+d][q]
    int mh = bid >> 2;
    int mat = mh / 3, h = mh - mat*3;
    int tile = bid & 3; int tp = (tile>>1)*64, tq = (tile&1)*64;
    const float* W  = (mat==0)?W1A:(mat==1)?WnA:(mat==2)?W1B:WnB;
    const float* Wl = (mat<2)? WlA : WlB;
    int tid = threadIdx.x;
    int tq4 = (tid&15)<<2, tp4 = (tid>>4)<<2;
    float acc[4][4] = {};
    for (int d0=0; d0<128; d0+=32){
      {
        int p = tid>>3, dd = (tid&7)<<2;
        float4 a0 = *(const float4*)&W[(size_t)(tp+p)*HD + h*128 + d0 + dd];
        float4 a1 = *(const float4*)&W[(size_t)(tp+p+32)*HD + h*128 + d0 + dd];
        As[dd+0][p]=a0.x; As[dd+1][p]=a0.y; As[dd+2][p]=a0.z; As[dd+3][p]=a0.w;
        As[dd+0][p+32]=a1.x; As[dd+1][p+32]=a1.y; As[dd+2][p+32]=a1.z; As[dd+3][p+32]=a1.w;
      }
      {
        int dd = tid>>4, q4 = (tid&15)<<2;
        float4 b0 = *(const float4*)&Wl[(size_t)(h*128+d0+dd)*128 + tq + q4];
        float4 b1 = *(const float4*)&Wl[(size_t)(h*128+d0+dd+16)*128 + tq + q4];
        Bs[dd][q4+0]=b0.x; Bs[dd][q4+1]=b0.y; Bs[dd][q4+2]=b0.z; Bs[dd][q4+3]=b0.w;
        Bs[dd+16][q4+0]=b1.x; Bs[dd+16][q4+1]=b1.y; Bs[dd+16][q4+2]=b1.z; Bs[dd+16][q4+3]=b1.w;
      }
      __syncthreads();
      #pragma unroll
      for (int k=0;k<32;k++){
        float a[4], bb[4];
        #pragma unroll
        for (int i=0;i<4;i++) a[i] = As[k][tp4+i];
        #pragma unroll
        for (int jq=0;jq<4;jq++) bb[jq] = Bs[k][tq4+jq];
        #pragma unroll
        for (int i=0;i<4;i++)
          #pragma unroll
          for (int jq=0;jq<4;jq++)
            acc[i][jq] += a[i]*bb[jq];
      }
      __syncthreads();
    }
    #pragma unroll
    for (int jq=0;jq<4;jq++)
      #pragma unroll
      for (int i=0;i<4;i++)
        MT[(size_t)mat*49152 + (size_t)(tq+tq4+jq)*HD + h*128 + tp+tp4+i] = f2bf(acc[i][jq]);
  } else if (bid < 816){
    int idx = (bid-48)*4 + wv;
    int mat = idx / 768; int rem = idx - mat*768;
    int j = rem >> 7, k = rem & 127;
    int h = (j >= 3) ? j-3 : j; bool isr = j >= 3;
    const float* W = (mat==0)?W1A:(mat==1)?WnA:(mat==2)?W1B:WnB;
    const float* a;
    if (mat==0)      a = isr?ar1A:al1A;
    else if (mat==1) a = isr?arnA:alnA;
    else if (mat==2) a = isr?ar1B:al1B;
    else             a = isr?arnB:alnB;
    float s = W[(size_t)k*HD + h*128 + lane]      * a[h*128 + lane]
            + W[(size_t)k*HD + h*128 + 64 + lane] * a[h*128 + 64 + lane];
    #pragma unroll
    for (int o=32;o;o>>=1) s += __shfl_xor(s,o);
    if (lane == 0) V[(size_t)mat*768 + j*128 + k] = s;
  } else if (bid < 944){
    int idx = (bid-816)*4 + wv;
    int mat = idx >> 7, q = idx & 127;
    const float* bvec = (mat==0)?b1A:(mat==1)?bnA:(mat==2)?b1B:bnB;
    const float* Wl = (mat<2)?WlA:WlB;
    const float* bl = (mat<2)?blA:blB;
    float s = 0.f;
    #pragma unroll
    for (int r=0;r<6;r++){
      int j = r*64 + lane;
      s += bvec[j]*Wl[(size_t)j*128 + q];
    }
    #pragma unroll
    for (int o=32;o;o>>=1) s += __shfl_xor(s,o);
    if (lane == 0) cbuf[mat*128 + q] = s + bl[q];
  } else {
    int bb = bid - 944; int isB = bb >= nbE;
    const int* src = isB ? srcB : srcA;
    const int* dst = isB ? dstB : dstA;
    int* cnt  = isB ? cntB : cntA;
    int* slot = isB ? slotB : slotA;
    int i = (isB ? bb-nbE : bb)*256 + threadIdx.x;
    if (i < ne){
      int d = dst[i];
      int p = atomicAdd(&cnt[d], 1);
      if (p < ELL) slot[d*ELL + p] = src[i];
    }
  }
}

// ---------------- conv feats -> bf16, fused layer-1 el/er ----------------
__global__ __launch_bounds__(256) void conv_elr1(
    const float* __restrict__ fA, const float* __restrict__ fB,
    unsigned short* __restrict__ XA, unsigned short* __restrict__ XB,
    const float* __restrict__ V,
    float* __restrict__ el, float* __restrict__ er){
  int gn = blockIdx.x*4 + (threadIdx.x>>6);      // 0..2*NN-1
  int lane = threadIdx.x & 63;
  int b = gn >= NN; int n = b ? gn - NN : gn;
  const float* feats = b ? fB : fA;
  unsigned short* X = b ? XB : XA;
  const float* Vb = V + (size_t)(b*2 + 0)*768;
  float2 xv = ((const float2*)feats)[(size_t)n*64 + lane];
  ((unsigned*)(X + (size_t)n*EMB))[lane] =
      (unsigned)f2bf(xv.x) | ((unsigned)f2bf(xv.y)<<16);
  float x0 = bf2f((unsigned)f2bf(xv.x)), x1 = bf2f((unsigned)f2bf(xv.y));
  int c0 = 2*lane;
  #pragma unroll
  for (int j=0;j<6;j++){
    float v = x0*Vb[j*128 + c0] + x1*Vb[j*128 + c0 + 1];
    #pragma unroll
    for (int o=32;o;o>>=1) v += __shfl_xor(v,o);
    if (lane == 0){
      if (j < 3) el[(size_t)gn*4 + j] = v;
      else       er[(size_t)gn*4 + (j-3)] = v;
    }
  }
}

// ---------------- fused GAT layer: pair-interleaved gather -> LDS U -> MFMA ----
// grid = NLB blocks; block handles node-halves base and base+10000 of ONE branch.
// branch = bid&1 (XCD parity), base = (bid>>1)*16
__global__ __launch_bounds__(256) void layer_fused(
    const unsigned short* __restrict__ X0, const unsigned short* __restrict__ X1,
    const float* __restrict__ el, const float* __restrict__ er,
    const int* __restrict__ cntA, const int* __restrict__ cntB,
    const int* __restrict__ slotA, const int* __restrict__ slotB,
    const unsigned short* __restrict__ MT_A, const unsigned short* __restrict__ MT_B,
    const float* __restrict__ cb_A, const float* __restrict__ cb_B,
    const float* __restrict__ V, int vsel,
    float* __restrict__ elN, float* __restrict__ erN,
    unsigned short* __restrict__ Xo0, unsigned short* __restrict__ Xo1){
  __shared__ unsigned short Ul[16][392];     // 16 x (384+8 pad) bf16 = 12.25 KB
  __shared__ float part[4][16][6];           // elr partials
  int wv = threadIdx.x >> 6, lane = threadIdx.x & 63;
  int bid = blockIdx.x;                      // 0..NLB-1
  int b = bid & 1;                           // XCD parity: one branch per XCD
  int base0 = (bid >> 1) * 16;

  // branch-dependent state: identical for both units (hoisted)
  const unsigned short* X = b ? X1 : X0;
  const int* cnt  = b ? cntB : cntA;
  const int* slot = b ? slotB : slotA;
  const float* elb = el + (size_t)b*NN*4;
  const float* erb = er + (size_t)b*NN*4;
  const unsigned* Xw = (const unsigned*)X;
  const unsigned short* MTb = b ? MT_B : MT_A;
  const float* cbb = b ? cb_B : cb_A;
  unsigned short* Xout = b ? Xo1 : Xo0;
  int l16 = lane & 15, lq = lane >> 4;
  int col0 = wv*32 + l16;
  int col1 = col0 + 16;
  const unsigned short* bp0 = MTb + (size_t)col0*HD + lq*8;
  const unsigned short* bp1 = MTb + (size_t)col1*HD + lq*8;
  float cv0 = cbb[col0], cv1 = cbb[col1];
  float vv0[6], vv1[6];
  if (vsel >= 0){
    const float* Vv = V + (size_t)(b*2 + vsel)*768;
    #pragma unroll
    for (int j=0;j<6;j++){ vv0[j] = Vv[j*128 + col0]; vv1[j] = Vv[j*128 + col1]; }
  }

  #pragma unroll 1
  for (int half = 0; half < 2; half++){
    int base = base0 + half*10000;
    if (half) __syncthreads();               // protect Ul/part reuse across units

    // ---- phase 1: two node-pairs; softmax interleaved, aggregation 8 chains ----
    #pragma unroll
    for (int pp = 0; pp < 2; pp++){
      int dg_[2]; int s_[2]; float e_[2][3];
      #pragma unroll
      for (int j=0;j<2;j++){
        int n = base + wv*4 + pp*2 + j;
        int dg = cnt[n]; if (dg > ELL) dg = ELL;
        dg_[j] = dg;
        float4 ev4 = *(const float4*)(erb + (size_t)n*4);
        int s = 0;
        float q0=-3e38f, q1=-3e38f, q2=-3e38f;
        if (lane < dg){
          s = slot[n*ELL + lane];
          float4 lv = *(const float4*)(elb + (size_t)s*4);
          float t0 = lv.x+ev4.x; q0 = t0>0.f ? t0 : 0.2f*t0;
          float t1 = lv.y+ev4.y; q1 = t1>0.f ? t1 : 0.2f*t1;
          float t2 = lv.z+ev4.z; q2 = t2>0.f ? t2 : 0.2f*t2;
        }
        s_[j] = s; e_[j][0]=q0; e_[j][1]=q1; e_[j][2]=q2;
      }
      float m_[2][3];
      #pragma unroll
      for (int j=0;j<2;j++)
        #pragma unroll
        for (int h=0;h<3;h++) m_[j][h] = e_[j][h];
      #pragma unroll
      for (int o=32;o;o>>=1)
        #pragma unroll
        for (int j=0;j<2;j++)
          #pragma unroll
          for (int h=0;h<3;h++) m_[j][h] = fmaxf(m_[j][h], __shfl_xor(m_[j][h],o));
      float p_[2][3], d_[2][3];
      #pragma unroll
      for (int j=0;j<2;j++)
        #pragma unroll
        for (int h=0;h<3;h++){ p_[j][h] = __expf(e_[j][h]-m_[j][h]); d_[j][h] = p_[j][h]; }
      #pragma unroll
      for (int o=32;o;o>>=1)
        #pragma unroll
        for (int j=0;j<2;j++)
          #pragma unroll
          for (int h=0;h<3;h++) d_[j][h] += __shfl_xor(d_[j][h],o);
      int ai_[2][3];
      #pragma unroll
      for (int j=0;j<2;j++)
        #pragma unroll
        for (int h=0;h<3;h++) ai_[j][h] = __float_as_int(p_[j][h]/d_[j][h]);

      // aggregation: 2 nodes x unroll-4 = 8 gathers in flight
      int degmax = dg_[0] > dg_[1] ? dg_[0] : dg_[1];
      int npad = (degmax + 3) & ~3;
      float acc_[2][6] = {};
      for (int e4 = 0; e4 < npad; e4 += 4){
        #pragma unroll
        for (int u = 0; u < 4; u++){
          int idx = e4 + u;
          #pragma unroll
          for (int j=0;j<2;j++){
            int sl = __builtin_amdgcn_readlane(s_[j], idx);
            float w0 = __int_as_float(__builtin_amdgcn_readlane(ai_[j][0], idx));
            float w1 = __int_as_float(__builtin_amdgcn_readlane(ai_[j][1], idx));
            float w2 = __int_as_float(__builtin_amdgcn_readlane(ai_[j][2], idx));
            unsigned xu = Xw[(size_t)sl*64 + lane];
            float lo = __int_as_float(xu << 16);
            float hi = __int_as_float(xu & 0xffff0000u);
            acc_[j][0] += w0*lo; acc_[j][1] += w0*hi;
            acc_[j][2] += w1*lo; acc_[j][3] += w1*hi;
            acc_[j][4] += w2*lo; acc_[j][5] += w2*hi;
          }
        }
      }
      #pragma unroll
      for (int j=0;j<2;j++){
        unsigned* urow = (unsigned*)&Ul[wv*4 + pp*2 + j][0];
        urow[lane]     = (unsigned)f2bf(acc_[j][0]) | ((unsigned)f2bf(acc_[j][1])<<16);
        urow[64+lane]  = (unsigned)f2bf(acc_[j][2]) | ((unsigned)f2bf(acc_[j][3])<<16);
        urow[128+lane] = (unsigned)f2bf(acc_[j][4]) | ((unsigned)f2bf(acc_[j][5])<<16);
      }
    }
    __syncthreads();

    // ---- phase 2: C[16 nodes][128] = U[16][384] @ M[384][128] via MFMA ----
    f32x4 acc0 = {0.f,0.f,0.f,0.f}, acc1 = {0.f,0.f,0.f,0.f};
    #pragma unroll
    for (int k0 = 0; k0 < HD; k0 += 32){
      short8 af = *(const short8*)&Ul[l16][k0 + lq*8];
      short8 b0 = *(const short8*)&bp0[k0];
      short8 b1 = *(const short8*)&bp1[k0];
      acc0 = __builtin_amdgcn_mfma_f32_16x16x32_bf16(af, b0, acc0, 0, 0, 0);
      acc1 = __builtin_amdgcn_mfma_f32_16x16x32_bf16(af, b1, acc1, 0, 0, 0);
    }

    // ---- epilogue: bias, bf16 round, store X_next, elr_next ----
    #pragma unroll
    for (int r = 0; r < 4; r++){
      int nloc = lq*4 + r;
      int n = base + nloc;
      float x0 = acc0[r] + cv0, x1 = acc1[r] + cv1;
      unsigned short xb0 = f2bf(x0), xb1 = f2bf(x1);
      Xout[(size_t)n*EMB + col0] = xb0;
      Xout[(size_t)n*EMB + col1] = xb1;
      if (vsel >= 0){
        float xr0 = bf2f(xb0), xr1 = bf2f(xb1);
        float p[6];
        #pragma unroll
        for (int j=0;j<6;j++) p[j] = xr0*vv0[j] + xr1*vv1[j];
        #pragma unroll
        for (int j=0;j<6;j++){
          #pragma unroll
          for (int o=1;o<16;o<<=1) p[j] += __shfl_xor(p[j], o);
        }
        if (l16 == 0){
          #pragma unroll
          for (int j=0;j<6;j++) part[wv][nloc][j] = p[j];
        }
      }
    }
    if (vsel >= 0){
      __syncthreads();
      int t = threadIdx.x;
      if (t < 96){
        int nloc = t / 6, j = t - (t/6)*6;
        float s2 = part[0][nloc][j] + part[1][nloc][j] + part[2][nloc][j] + part[3][nloc][j];
        size_t gn = (size_t)b*NN + base + nloc;
        if (j < 3) elN[gn*4 + j] = s2;
        else       erN[gn*4 + (j-3)] = s2;
      }
    }
  }
}

// ---------------- pooling: contiguous segments via binary search, no atomics ----
__device__ inline int lbound(const int* __restrict__ a, int n, int v){
  int lo = 0, hi = n;
  while (lo < hi){ int mid = (lo+hi)>>1; if (a[mid] < v) lo = mid+1; else hi = mid; }
  return lo;
}

__global__ __launch_bounds__(512) void pool_kernel(
    const unsigned short* __restrict__ X0, const unsigned short* __restrict__ X1,
    const int* __restrict__ gidA, const int* __restrict__ gidB,
    float* __restrict__ ps){
  int bg = blockIdx.x;                 // 0..2*GG-1
  int b = bg >= GG; int g = b ? bg-GG : bg;
  const unsigned short* X = b ? X1 : X0;
  const int* gid = b ? gidB : gidA;
  int lo = lbound(gid, NN, g), hi = lbound(gid, NN, g+1);
  int t = threadIdx.x;
  int rl = t >> 6, c2 = t & 63;        // 8 row-lanes x 64 u32-cols
  float ax = 0.f, ay = 0.f;
  for (int n = lo + rl; n < hi; n += 8){
    unsigned u = ((const unsigned*)(X + (size_t)n*EMB))[c2];
    ax += bf2f(u & 0xFFFFu); ay += bf2f(u >> 16);
  }
  __shared__ float sh[8][128];
  sh[rl][2*c2] = ax; sh[rl][2*c2+1] = ay;
  __syncthreads();
  if (t < 128){
    float s = 0.f;
    #pragma unroll
    for (int r=0;r<8;r++) s += sh[r][t];
    ps[(size_t)bg*EMB + t] = s / (float)(hi - lo);
  }
}

// ---------------- final ----------------
__global__ void final_kernel(const float* __restrict__ ps,
                             const float* __restrict__ Wo, const float* __restrict__ bo,
                             float* __restrict__ out){
  int g = blockIdx.x*4 + (threadIdx.x>>6);
  int lane = threadIdx.x & 63;
  if (g >= GG) return;
  float v = 0.f;
  #pragma unroll
  for (int r=0;r<4;r++){
    int k = r*64 + lane;
    float cv = (k < EMB) ? ps[(size_t)g*EMB + k]
                         : ps[(size_t)(GG + g)*EMB + (k-EMB)];
    v += cv * Wo[k];
  }
  #pragma unroll
  for (int o=32;o;o>>=1) v += __shfl_xor(v,o);
  if (lane == 0) out[g] = v + bo[0];
}

// ---------------- launcher ----------------
extern "C" void kernel_launch(void* const* d_in, const int* in_sizes, int n_in,
                              void* d_out, int out_size, void* d_ws, size_t ws_size,
                              hipStream_t stream){
  const float* featsA = (const float*)d_in[0];
  const float* featsB = (const float*)d_in[1];
  const int* srcA = (const int*)d_in[2];
  const int* dstA = (const int*)d_in[3];
  const int* gidA = (const int*)d_in[4];
  const int* srcB = (const int*)d_in[5];
  const int* dstB = (const int*)d_in[6];
  const int* gidB = (const int*)d_in[7];
  const int EE = in_sizes[2];
  const float* P[2][10];
  for (int b=0;b<2;b++)
    for (int j=0;j<10;j++)
      P[b][j] = (const float*)d_in[8 + b*10 + j];
  const float* Wo = (const float*)d_in[28];
  const float* bo = (const float*)d_in[29];
  float* out = (float*)d_out;

  char* ws = (char*)d_ws;
  size_t o = 0;
  auto alloc = [&](size_t bytes)->char*{
    char* p = ws + o; o += (bytes + 255) & ~(size_t)255; return p;
  };
  unsigned short* fbf[2] = {(unsigned short*)alloc((size_t)NN*FF*2),
                            (unsigned short*)alloc((size_t)NN*FF*2)};
  unsigned short* Xa[2] = {(unsigned short*)alloc((size_t)NN*EMB*2),
                           (unsigned short*)alloc((size_t)NN*EMB*2)};
  unsigned short* Xb[2] = {(unsigned short*)alloc((size_t)NN*EMB*2),
                           (unsigned short*)alloc((size_t)NN*EMB*2)};
  unsigned short* MT = (unsigned short*)alloc((size_t)4*49152*2);
  float* V    = (float*)alloc((size_t)4*768*4);
  float* cbuf = (float*)alloc((size_t)4*128*4);
  float* el0  = (float*)alloc((size_t)2*NN*4*4);
  float* er0  = (float*)alloc((size_t)2*NN*4*4);
  float* el1  = (float*)alloc((size_t)2*NN*4*4);
  float* er1  = (float*)alloc((size_t)2*NN*4*4);
  float* el2  = (float*)alloc((size_t)2*NN*4*4);
  float* er2  = (float*)alloc((size_t)2*NN*4*4);
  int*   cntA = (int*)alloc((size_t)2*NN*4);
  int*   cntB = cntA + NN;
  int*   slotA= (int*)alloc((size_t)NN*ELL*4);
  int*   slotB= (int*)alloc((size_t)NN*ELL*4);
  float* ps   = (float*)alloc((size_t)2*GG*EMB*4);

  const int nbE = (EE + 255)/256;
  const int nwB = 2*NN/4;

  hipMemsetAsync(cntA, 0, (size_t)2*NN*4, stream);
  prep<<<944 + 2*nbE, 256, 0, stream>>>(
      P[0][0],P[0][1],P[0][2], P[0][4],P[0][5],P[0][6],
      P[1][0],P[1][1],P[1][2], P[1][4],P[1][5],P[1][6],
      P[0][8],P[0][9], P[1][8],P[1][9],
      P[0][3],P[0][7], P[1][3],P[1][7],
      MT, V, cbuf,
      srcA,dstA, srcB,dstB, cntA,cntB, slotA,slotB, EE, nbE);
  conv_elr1<<<nwB,256,0,stream>>>(featsA, featsB, fbf[0], fbf[1], V, el0, er0);

  // layer 1: X=feats, M = composed(W1,Wl), elr_next via V lsel=1
  layer_fused<<<NLB,256,0,stream>>>(fbf[0], fbf[1], el0, er0, cntA,cntB, slotA,slotB,
                                    MT + 0*49152, MT + 2*49152,
                                    cbuf + 0*128, cbuf + 2*128,
                                    V, 1, el1, er1, Xa[0], Xa[1]);
  // layer 2: M = composed(Wn,Wl)
  layer_fused<<<NLB,256,0,stream>>>(Xa[0], Xa[1], el1, er1, cntA,cntB, slotA,slotB,
                                    MT + 1*49152, MT + 3*49152,
                                    cbuf + 1*128, cbuf + 3*128,
                                    V, 1, el2, er2, Xb[0], Xb[1]);
  // layer 3: no elr_next
  layer_fused<<<NLB,256,0,stream>>>(Xb[0], Xb[1], el2, er2, cntA,cntB, slotA,slotB,
                                    MT + 1*49152, MT + 3*49152,
                                    cbuf + 1*128, cbuf + 3*128,
                                    V, -1, nullptr, nullptr, Xa[0], Xa[1]);

  // pooling + final
  pool_kernel<<<2*GG,512,0,stream>>>(Xa[0],Xa[1], gidA,gidB, ps);
  final_kernel<<<(GG+3)/4,256,0,stream>>>(ps, Wo, bo, out);
}

// Round 14
// 255.156 us; speedup vs baseline: 1.4412x; 1.3788x over previous
//
#include <hip/hip_runtime.h>
#include <hip/hip_bf16.h>
#include <math.h>

#define NN  20000
#define FF  128
#define EMB 128
#define HH  3
#define GG  128
#define HD  384   // H*EMB
#define ELL 64    // max degree capacity (deg = 1+Poisson(16); P(>64) ~ 1e-14)

typedef __attribute__((ext_vector_type(8))) short short8;
typedef __attribute__((ext_vector_type(4))) float f32x4;

__device__ inline float bf2f(unsigned int u){
  union{unsigned int i; float f;} v; v.i = u<<16; return v.f;
}
__device__ inline unsigned short f2bf(float f){
  union{unsigned int i; float f;} v; v.f = f;
  unsigned r = v.i + 0x7FFFu + ((v.i>>16)&1u);
  return (unsigned short)(r>>16);
}

// ---------------- prep: MT, V, cbuf + ELL count_fill (one launch) ----------------
// blocks [0,48): MT; [48,816): V; [816,944): cbuf; [944, 944+2*nbE): count_fill
__global__ __launch_bounds__(256) void prep(
    const float* __restrict__ W1A, const float* __restrict__ al1A, const float* __restrict__ ar1A,
    const float* __restrict__ WnA, const float* __restrict__ alnA, const float* __restrict__ arnA,
    const float* __restrict__ W1B, const float* __restrict__ al1B, const float* __restrict__ ar1B,
    const float* __restrict__ WnB, const float* __restrict__ alnB, const float* __restrict__ arnB,
    const float* __restrict__ WlA, const float* __restrict__ blA,
    const float* __restrict__ WlB, const float* __restrict__ blB,
    const float* __restrict__ b1A, const float* __restrict__ bnA,
    const float* __restrict__ b1B, const float* __restrict__ bnB,
    unsigned short* __restrict__ MT, float* __restrict__ V, float* __restrict__ cbuf,
    const int* __restrict__ srcA, const int* __restrict__ dstA,
    const int* __restrict__ srcB, const int* __restrict__ dstB,
    int* __restrict__ cntA, int* __restrict__ cntB,
    int* __restrict__ slotA, int* __restrict__ slotB, int ne, int nbE){
  __shared__ float As[32][65];   // [d][p]
  __shared__ float Bs[32][65];   // [d][q]
  int bid = blockIdx.x;
  int wv = threadIdx.x >> 6, lane = threadIdx.x & 63;

  if (bid < 48){
    // composed weights MT[mat][q][h*128+p] = sum_d W[p][h*128+d]*Wl[h*128+d][q]
    int mh = bid >> 2;
    int mat = mh / 3, h = mh - mat*3;
    int tile = bid & 3; int tp = (tile>>1)*64, tq = (tile&1)*64;
    const float* W  = (mat==0)?W1A:(mat==1)?WnA:(mat==2)?W1B:WnB;
    const float* Wl = (mat<2)? WlA : WlB;
    int tid = threadIdx.x;
    int tq4 = (tid&15)<<2, tp4 = (tid>>4)<<2;
    float acc[4][4] = {};
    for (int d0=0; d0<128; d0+=32){
      {
        int p = tid>>3, dd = (tid&7)<<2;
        float4 a0 = *(const float4*)&W[(size_t)(tp+p)*HD + h*128 + d0 + dd];
        float4 a1 = *(const float4*)&W[(size_t)(tp+p+32)*HD + h*128 + d0 + dd];
        As[dd+0][p]=a0.x; As[dd+1][p]=a0.y; As[dd+2][p]=a0.z; As[dd+3][p]=a0.w;
        As[dd+0][p+32]=a1.x; As[dd+1][p+32]=a1.y; As[dd+2][p+32]=a1.z; As[dd+3][p+32]=a1.w;
      }
      {
        int dd = tid>>4, q4 = (tid&15)<<2;
        float4 b0 = *(const float4*)&Wl[(size_t)(h*128+d0+dd)*128 + tq + q4];
        float4 b1 = *(const float4*)&Wl[(size_t)(h*128+d0+dd+16)*128 + tq + q4];
        Bs[dd][q4+0]=b0.x; Bs[dd][q4+1]=b0.y; Bs[dd][q4+2]=b0.z; Bs[dd][q4+3]=b0.w;
        Bs[dd+16][q4+0]=b1.x; Bs[dd+16][q4+1]=b1.y; Bs[dd+16][q4+2]=b1.z; Bs[dd+16][q4+3]=b1.w;
      }
      __syncthreads();
      #pragma unroll
      for (int k=0;k<32;k++){
        float a[4], bb[4];
        #pragma unroll
        for (int i=0;i<4;i++) a[i] = As[k][tp4+i];
        #pragma unroll
        for (int jq=0;jq<4;jq++) bb[jq] = Bs[k][tq4+jq];
        #pragma unroll
        for (int i=0;i<4;i++)
          #pragma unroll
          for (int jq=0;jq<4;jq++)
            acc[i][jq] += a[i]*bb[jq];
      }
      __syncthreads();
    }
    #pragma unroll
    for (int jq=0;jq<4;jq++)
      #pragma unroll
      for (int i=0;i<4;i++)
        MT[(size_t)mat*49152 + (size_t)(tq+tq4+jq)*HD + h*128 + tp+tp4+i] = f2bf(acc[i][jq]);
  } else if (bid < 816){
    int idx = (bid-48)*4 + wv;
    int mat = idx / 768; int rem = idx - mat*768;
    int j = rem >> 7, k = rem & 127;
    int h = (j >= 3) ? j-3 : j; bool isr = j >= 3;
    const float* W = (mat==0)?W1A:(mat==1)?WnA:(mat==2)?W1B:WnB;
    const float* a;
    if (mat==0)      a = isr?ar1A:al1A;
    else if (mat==1) a = isr?arnA:alnA;
    else if (mat==2) a = isr?ar1B:al1B;
    else             a = isr?arnB:alnB;
    float s = W[(size_t)k*HD + h*128 + lane]      * a[h*128 + lane]
            + W[(size_t)k*HD + h*128 + 64 + lane] * a[h*128 + 64 + lane];
    #pragma unroll
    for (int o=32;o;o>>=1) s += __shfl_xor(s,o);
    if (lane == 0) V[(size_t)mat*768 + j*128 + k] = s;
  } else if (bid < 944){
    int idx = (bid-816)*4 + wv;
    int mat = idx >> 7, q = idx & 127;
    const float* bvec = (mat==0)?b1A:(mat==1)?bnA:(mat==2)?b1B:bnB;
    const float* Wl = (mat<2)?WlA:WlB;
    const float* bl = (mat<2)?blA:blB;
    float s = 0.f;
    #pragma unroll
    for (int r=0;r<6;r++){
      int j = r*64 + lane;
      s += bvec[j]*Wl[(size_t)j*128 + q];
    }
    #pragma unroll
    for (int o=32;o;o>>=1) s += __shfl_xor(s,o);
    if (lane == 0) cbuf[mat*128 + q] = s + bl[q];
  } else {
    int bb = bid - 944; int isB = bb >= nbE;
    const int* src = isB ? srcB : srcA;
    const int* dst = isB ? dstB : dstA;
    int* cnt  = isB ? cntB : cntA;
    int* slot = isB ? slotB : slotA;
    int i = (isB ? bb-nbE : bb)*256 + threadIdx.x;
    if (i < ne){
      int d = dst[i];
      int p = atomicAdd(&cnt[d], 1);
      if (p < ELL) slot[d*ELL + p] = src[i];
    }
  }
}

// ---------------- conv feats -> bf16, fused layer-1 el/er ----------------
__global__ __launch_bounds__(256) void conv_elr1(
    const float* __restrict__ fA, const float* __restrict__ fB,
    unsigned short* __restrict__ XA, unsigned short* __restrict__ XB,
    const float* __restrict__ V,
    float* __restrict__ el, float* __restrict__ er){
  int gn = blockIdx.x*4 + (threadIdx.x>>6);      // 0..2*NN-1
  int lane = threadIdx.x & 63;
  int b = gn >= NN; int n = b ? gn - NN : gn;
  const float* feats = b ? fB : fA;
  unsigned short* X = b ? XB : XA;
  const float* Vb = V + (size_t)(b*2 + 0)*768;
  float2 xv = ((const float2*)feats)[(size_t)n*64 + lane];
  ((unsigned*)(X + (size_t)n*EMB))[lane] =
      (unsigned)f2bf(xv.x) | ((unsigned)f2bf(xv.y)<<16);
  float x0 = bf2f((unsigned)f2bf(xv.x)), x1 = bf2f((unsigned)f2bf(xv.y));
  int c0 = 2*lane;
  #pragma unroll
  for (int j=0;j<6;j++){
    float v = x0*Vb[j*128 + c0] + x1*Vb[j*128 + c0 + 1];
    #pragma unroll
    for (int o=32;o;o>>=1) v += __shfl_xor(v,o);
    if (lane == 0){
      if (j < 3) el[(size_t)gn*4 + j] = v;
      else       er[(size_t)gn*4 + (j-3)] = v;
    }
  }
}

// ---------------- fused GAT layer: pair-interleaved gather -> LDS U -> MFMA ----
// block = 16 nodes (one branch); branch = bid&1 (XCD parity), node base = (bid>>1)*16
__global__ __launch_bounds__(256) void layer_fused(
    const unsigned short* __restrict__ X0, const unsigned short* __restrict__ X1,
    const float* __restrict__ el, const float* __restrict__ er,
    const int* __restrict__ cntA, const int* __restrict__ cntB,
    const int* __restrict__ slotA, const int* __restrict__ slotB,
    const unsigned short* __restrict__ MT_A, const unsigned short* __restrict__ MT_B,
    const float* __restrict__ cb_A, const float* __restrict__ cb_B,
    const float* __restrict__ V, int vsel,
    float* __restrict__ elN, float* __restrict__ erN,
    unsigned short* __restrict__ Xo0, unsigned short* __restrict__ Xo1){
  __shared__ unsigned short Ul[16][392];     // 16 x (384+8 pad) bf16 = 12.25 KB
  __shared__ float part[4][16][6];           // elr partials
  int wv = threadIdx.x >> 6, lane = threadIdx.x & 63;
  int bid = blockIdx.x;                      // 0..2499
  int b = bid & 1;                           // XCD parity: one branch per XCD
  int base = (bid >> 1) * 16;
  const unsigned short* X = b ? X1 : X0;
  const int* cnt  = b ? cntB : cntA;
  const int* slot = b ? slotB : slotA;
  const float* elb = el + (size_t)b*NN*4;
  const float* erb = er + (size_t)b*NN*4;
  const unsigned* Xw = (const unsigned*)X;

  // ---- phase 1: two node-pairs; softmax interleaved, aggregation 8 chains ----
  #pragma unroll
  for (int pp = 0; pp < 2; pp++){
    int dg_[2]; int s_[2]; float e_[2][3];
    #pragma unroll
    for (int j=0;j<2;j++){
      int n = base + wv*4 + pp*2 + j;
      int dg = cnt[n]; if (dg > ELL) dg = ELL;
      dg_[j] = dg;
      float4 ev4 = *(const float4*)(erb + (size_t)n*4);
      int s = 0;
      float q0=-3e38f, q1=-3e38f, q2=-3e38f;
      if (lane < dg){
        s = slot[n*ELL + lane];
        float4 lv = *(const float4*)(elb + (size_t)s*4);
        float t0 = lv.x+ev4.x; q0 = t0>0.f ? t0 : 0.2f*t0;
        float t1 = lv.y+ev4.y; q1 = t1>0.f ? t1 : 0.2f*t1;
        float t2 = lv.z+ev4.z; q2 = t2>0.f ? t2 : 0.2f*t2;
      }
      s_[j] = s; e_[j][0]=q0; e_[j][1]=q1; e_[j][2]=q2;
    }
    float m_[2][3];
    #pragma unroll
    for (int j=0;j<2;j++)
      #pragma unroll
      for (int h=0;h<3;h++) m_[j][h] = e_[j][h];
    #pragma unroll
    for (int o=32;o;o>>=1)
      #pragma unroll
      for (int j=0;j<2;j++)
        #pragma unroll
        for (int h=0;h<3;h++) m_[j][h] = fmaxf(m_[j][h], __shfl_xor(m_[j][h],o));
    float p_[2][3], d_[2][3];
    #pragma unroll
    for (int j=0;j<2;j++)
      #pragma unroll
      for (int h=0;h<3;h++){ p_[j][h] = __expf(e_[j][h]-m_[j][h]); d_[j][h] = p_[j][h]; }
    #pragma unroll
    for (int o=32;o;o>>=1)
      #pragma unroll
      for (int j=0;j<2;j++)
        #pragma unroll
        for (int h=0;h<3;h++) d_[j][h] += __shfl_xor(d_[j][h],o);
    int ai_[2][3];
    #pragma unroll
    for (int j=0;j<2;j++)
      #pragma unroll
      for (int h=0;h<3;h++) ai_[j][h] = __float_as_int(p_[j][h]/d_[j][h]);

    // aggregation: 2 nodes x unroll-4 = 8 gathers in flight
    int degmax = dg_[0] > dg_[1] ? dg_[0] : dg_[1];
    int npad = (degmax + 3) & ~3;
    float acc_[2][6] = {};
    for (int e4 = 0; e4 < npad; e4 += 4){
      #pragma unroll
      for (int u = 0; u < 4; u++){
        int idx = e4 + u;
        #pragma unroll
        for (int j=0;j<2;j++){
          int sl = __builtin_amdgcn_readlane(s_[j], idx);
          float w0 = __int_as_float(__builtin_amdgcn_readlane(ai_[j][0], idx));
          float w1 = __int_as_float(__builtin_amdgcn_readlane(ai_[j][1], idx));
          float w2 = __int_as_float(__builtin_amdgcn_readlane(ai_[j][2], idx));
          unsigned xu = Xw[(size_t)sl*64 + lane];
          float lo = __int_as_float(xu << 16);
          float hi = __int_as_float(xu & 0xffff0000u);
          acc_[j][0] += w0*lo; acc_[j][1] += w0*hi;
          acc_[j][2] += w1*lo; acc_[j][3] += w1*hi;
          acc_[j][4] += w2*lo; acc_[j][5] += w2*hi;
        }
      }
    }
    #pragma unroll
    for (int j=0;j<2;j++){
      unsigned* urow = (unsigned*)&Ul[wv*4 + pp*2 + j][0];
      urow[lane]     = (unsigned)f2bf(acc_[j][0]) | ((unsigned)f2bf(acc_[j][1])<<16);
      urow[64+lane]  = (unsigned)f2bf(acc_[j][2]) | ((unsigned)f2bf(acc_[j][3])<<16);
      urow[128+lane] = (unsigned)f2bf(acc_[j][4]) | ((unsigned)f2bf(acc_[j][5])<<16);
    }
  }
  __syncthreads();

  // ---- phase 2: C[16 nodes][128] = U[16][384] @ M[384][128] via MFMA ----
  int l16 = lane & 15, lq = lane >> 4;
  const unsigned short* MTb = b ? MT_B : MT_A;
  int col0 = wv*32 + l16;
  int col1 = col0 + 16;
  const unsigned short* bp0 = MTb + (size_t)col0*HD + lq*8;
  const unsigned short* bp1 = MTb + (size_t)col1*HD + lq*8;
  f32x4 acc0 = {0.f,0.f,0.f,0.f}, acc1 = {0.f,0.f,0.f,0.f};
  #pragma unroll
  for (int k0 = 0; k0 < HD; k0 += 32){
    short8 af = *(const short8*)&Ul[l16][k0 + lq*8];
    short8 b0 = *(const short8*)&bp0[k0];
    short8 b1 = *(const short8*)&bp1[k0];
    acc0 = __builtin_amdgcn_mfma_f32_16x16x32_bf16(af, b0, acc0, 0, 0, 0);
    acc1 = __builtin_amdgcn_mfma_f32_16x16x32_bf16(af, b1, acc1, 0, 0, 0);
  }

  // ---- epilogue: bias, bf16 round, store X_next, elr_next ----
  const float* cbb = b ? cb_B : cb_A;
  unsigned short* Xout = b ? Xo1 : Xo0;
  float cv0 = cbb[col0], cv1 = cbb[col1];
  float vv0[6], vv1[6];
  if (vsel >= 0){
    const float* Vv = V + (size_t)(b*2 + vsel)*768;
    #pragma unroll
    for (int j=0;j<6;j++){ vv0[j] = Vv[j*128 + col0]; vv1[j] = Vv[j*128 + col1]; }
  }
  #pragma unroll
  for (int r = 0; r < 4; r++){
    int nloc = lq*4 + r;
    int n = base + nloc;
    float x0 = acc0[r] + cv0, x1 = acc1[r] + cv1;
    unsigned short xb0 = f2bf(x0), xb1 = f2bf(x1);
    Xout[(size_t)n*EMB + col0] = xb0;
    Xout[(size_t)n*EMB + col1] = xb1;
    if (vsel >= 0){
      float xr0 = bf2f(xb0), xr1 = bf2f(xb1);
      float p[6];
      #pragma unroll
      for (int j=0;j<6;j++) p[j] = xr0*vv0[j] + xr1*vv1[j];
      #pragma unroll
      for (int j=0;j<6;j++){
        #pragma unroll
        for (int o=1;o<16;o<<=1) p[j] += __shfl_xor(p[j], o);
      }
      if (l16 == 0){
        #pragma unroll
        for (int j=0;j<6;j++) part[wv][nloc][j] = p[j];
      }
    }
  }
  if (vsel >= 0){
    __syncthreads();
    int t = threadIdx.x;
    if (t < 96){
      int nloc = t / 6, j = t - (t/6)*6;
      float s2 = part[0][nloc][j] + part[1][nloc][j] + part[2][nloc][j] + part[3][nloc][j];
      size_t gn = (size_t)b*NN + base + nloc;
      if (j < 3) elN[gn*4 + j] = s2;
      else       erN[gn*4 + (j-3)] = s2;
    }
  }
}

// ---------------- pooling: contiguous segments via binary search, no atomics ----
__device__ inline int lbound(const int* __restrict__ a, int n, int v){
  int lo = 0, hi = n;
  while (lo < hi){ int mid = (lo+hi)>>1; if (a[mid] < v) lo = mid+1; else hi = mid; }
  return lo;
}

__global__ __launch_bounds__(512) void pool_kernel(
    const unsigned short* __restrict__ X0, const unsigned short* __restrict__ X1,
    const int* __restrict__ gidA, const int* __restrict__ gidB,
    float* __restrict__ ps){
  int bg = blockIdx.x;                 // 0..2*GG-1
  int b = bg >= GG; int g = b ? bg-GG : bg;
  const unsigned short* X = b ? X1 : X0;
  const int* gid = b ? gidB : gidA;
  int lo = lbound(gid, NN, g), hi = lbound(gid, NN, g+1);
  int t = threadIdx.x;
  int rl = t >> 6, c2 = t & 63;        // 8 row-lanes x 64 u32-cols
  float ax = 0.f, ay = 0.f;
  for (int n = lo + rl; n < hi; n += 8){
    unsigned u = ((const unsigned*)(X + (size_t)n*EMB))[c2];
    ax += bf2f(u & 0xFFFFu); ay += bf2f(u >> 16);
  }
  __shared__ float sh[8][128];
  sh[rl][2*c2] = ax; sh[rl][2*c2+1] = ay;
  __syncthreads();
  if (t < 128){
    float s = 0.f;
    #pragma unroll
    for (int r=0;r<8;r++) s += sh[r][t];
    ps[(size_t)bg*EMB + t] = s / (float)(hi - lo);
  }
}

// ---------------- final ----------------
__global__ void final_kernel(const float* __restrict__ ps,
                             const float* __restrict__ Wo, const float* __restrict__ bo,
                             float* __restrict__ out){
  int g = blockIdx.x*4 + (threadIdx.x>>6);
  int lane = threadIdx.x & 63;
  if (g >= GG) return;
  float v = 0.f;
  #pragma unroll
  for (int r=0;r<4;r++){
    int k = r*64 + lane;
    float cv = (k < EMB) ? ps[(size_t)g*EMB + k]
                         : ps[(size_t)(GG + g)*EMB + (k-EMB)];
    v += cv * Wo[k];
  }
  #pragma unroll
  for (int o=32;o;o>>=1) v += __shfl_xor(v,o);
  if (lane == 0) out[g] = v + bo[0];
}

// ---------------- launcher ----------------
extern "C" void kernel_launch(void* const* d_in, const int* in_sizes, int n_in,
                              void* d_out, int out_size, void* d_ws, size_t ws_size,
                              hipStream_t stream){
  const float* featsA = (const float*)d_in[0];
  const float* featsB = (const float*)d_in[1];
  const int* srcA = (const int*)d_in[2];
  const int* dstA = (const int*)d_in[3];
  const int* gidA = (const int*)d_in[4];
  const int* srcB = (const int*)d_in[5];
  const int* dstB = (const int*)d_in[6];
  const int* gidB = (const int*)d_in[7];
  const int EE = in_sizes[2];
  const float* P[2][10];
  for (int b=0;b<2;b++)
    for (int j=0;j<10;j++)
      P[b][j] = (const float*)d_in[8 + b*10 + j];
  const float* Wo = (const float*)d_in[28];
  const float* bo = (const float*)d_in[29];
  float* out = (float*)d_out;

  char* ws = (char*)d_ws;
  size_t o = 0;
  auto alloc = [&](size_t bytes)->char*{
    char* p = ws + o; o += (bytes + 255) & ~(size_t)255; return p;
  };
  unsigned short* fbf[2] = {(unsigned short*)alloc((size_t)NN*FF*2),
                            (unsigned short*)alloc((size_t)NN*FF*2)};
  unsigned short* Xa[2] = {(unsigned short*)alloc((size_t)NN*EMB*2),
                           (unsigned short*)alloc((size_t)NN*EMB*2)};
  unsigned short* Xb[2] = {(unsigned short*)alloc((size_t)NN*EMB*2),
                           (unsigned short*)alloc((size_t)NN*EMB*2)};
  unsigned short* MT = (unsigned short*)alloc((size_t)4*49152*2);
  float* V    = (float*)alloc((size_t)4*768*4);
  float* cbuf = (float*)alloc((size_t)4*128*4);
  float* el0  = (float*)alloc((size_t)2*NN*4*4);
  float* er0  = (float*)alloc((size_t)2*NN*4*4);
  float* el1  = (float*)alloc((size_t)2*NN*4*4);
  float* er1  = (float*)alloc((size_t)2*NN*4*4);
  float* el2  = (float*)alloc((size_t)2*NN*4*4);
  float* er2  = (float*)alloc((size_t)2*NN*4*4);
  int*   cntA = (int*)alloc((size_t)2*NN*4);
  int*   cntB = cntA + NN;
  int*   slotA= (int*)alloc((size_t)NN*ELL*4);
  int*   slotB= (int*)alloc((size_t)NN*ELL*4);
  float* ps   = (float*)alloc((size_t)2*GG*EMB*4);

  const int nbE = (EE + 255)/256;
  const int nwB = 2*NN/4;
  const int nLB = 2*NN/16;     // layer_fused blocks (2500)

  hipMemsetAsync(cntA, 0, (size_t)2*NN*4, stream);
  prep<<<944 + 2*nbE, 256, 0, stream>>>(
      P[0][0],P[0][1],P[0][2], P[0][4],P[0][5],P[0][6],
      P[1][0],P[1][1],P[1][2], P[1][4],P[1][5],P[1][6],
      P[0][8],P[0][9], P[1][8],P[1][9],
      P[0][3],P[0][7], P[1][3],P[1][7],
      MT, V, cbuf,
      srcA,dstA, srcB,dstB, cntA,cntB, slotA,slotB, EE, nbE);
  conv_elr1<<<nwB,256,0,stream>>>(featsA, featsB, fbf[0], fbf[1], V, el0, er0);

  // layer 1: X=feats, M = composed(W1,Wl), elr_next via V lsel=1
  layer_fused<<<nLB,256,0,stream>>>(fbf[0], fbf[1], el0, er0, cntA,cntB, slotA,slotB,
                                    MT + 0*49152, MT + 2*49152,
                                    cbuf + 0*128, cbuf + 2*128,
                                    V, 1, el1, er1, Xa[0], Xa[1]);
  // layer 2: M = composed(Wn,Wl)
  layer_fused<<<nLB,256,0,stream>>>(Xa[0], Xa[1], el1, er1, cntA,cntB, slotA,slotB,
                                    MT + 1*49152, MT + 3*49152,
                                    cbuf + 1*128, cbuf + 3*128,
                                    V, 1, el2, er2, Xb[0], Xb[1]);
  // layer 3: no elr_next
  layer_fused<<<nLB,256,0,stream>>>(Xb[0], Xb[1], el2, er2, cntA,cntB, slotA,slotB,
                                    MT + 1*49152, MT + 3*49152,
                                    cbuf + 1*128, cbuf + 3*128,
                                    V, -1, nullptr, nullptr, Xa[0], Xa[1]);

  // pooling + final
  pool_kernel<<<2*GG,512,0,stream>>>(Xa[0],Xa[1], gidA,gidB, ps);
  final_kernel<<<(GG+3)/4,256,0,stream>>>(ps, Wo, bo, out);
}